// Round 8
// baseline (185.904 us; speedup 1.0000x reference)
//
#include <hip/hip_runtime.h>
#include <stdint.h>

#define DIM   256
#define BATCH 8192
#define MCELL 4096

typedef unsigned long long u64;
typedef unsigned short u16;
typedef __attribute__((ext_vector_type(8))) short bf16x8;   // 8 bf16 = 4 VGPRs
typedef __attribute__((ext_vector_type(4))) float f32x4;

// ---------------- helpers ----------------
__device__ __forceinline__ u64 packMin(float v, unsigned idx) {
    unsigned u = __float_as_uint(v);
    u = (u & 0x80000000u) ? ~u : (u | 0x80000000u);   // order-preserving f32->u32
    return ((u64)u << 32) | (u64)idx;
}
__device__ __forceinline__ u16 f2bf(float f) {        // RN-even f32->bf16 (bits)
    unsigned u = __float_as_uint(f);
    u += 0x7fffu + ((u >> 16) & 1u);
    return (u16)(u >> 16);
}
__device__ __forceinline__ void gll16(const void* g, const char* l) {
    __builtin_amdgcn_global_load_lds(
        (const __attribute__((address_space(1))) unsigned int*)g,
        (__attribute__((address_space(3))) unsigned int*)l, 16, 0, 0);
}
__device__ __forceinline__ u64 umin64(u64 a, u64 b) { return a < b ? a : b; }
__device__ __forceinline__ u64 umax64(u64 a, u64 b) { return a < b ? b : a; }
__device__ __forceinline__ void ins2(u64& t1, u64& t2, u64 p) {
    u64 hi = umax64(p, t1);
    t1 = umin64(p, t1);
    t2 = umin64(t2, hi);
}
__device__ __forceinline__ void merge2(u64& a1, u64& a2, u64 o1, u64 o2) {
    u64 H1 = umax64(a1, o1);
    a1 = umin64(a1, o1);
    a2 = umin64(H1, umin64(a2, o2));
}
__device__ __forceinline__ void merge3(u64& a1, u64& a2, u64& a3,
                                       u64 o1, u64 o2, u64 o3) {
    u64 L1 = umin64(a1, o1), H1 = umax64(a1, o1);
    u64 L2 = umin64(a2, o2);
    u64 L3 = umin64(a3, o3);
    a1 = L1;
    a2 = umin64(H1, L2);
    a3 = umin64(umax64(H1, L2), L3);
}

// ---------------- prep: bf16 casts + w2 + scal, one launch ----------------
__global__ void k_prep(const float* __restrict__ X, const float* __restrict__ W,
                       u16* __restrict__ Xh, u16* __restrict__ Wh,
                       float* __restrict__ w2, const int* __restrict__ epoch_p,
                       float* __restrict__ scal) {
    const int blk = blockIdx.x;
    const int t = threadIdx.x;
    if (blk == 3072) {   // scal: E[64] table + alpha
        int raw = epoch_p[0];
        float ep = (raw >= 0 && raw < 100000) ? (float)raw : __int_as_float(raw);
        float radius = 32.0f - ep * (31.0f / 99.0f);
        float alpha  = 0.1f * (1.0f - ep / 100.0f);
        float rs = radius * 0.5f;
        float denom = 2.0f * rs * rs;
        if (t < 64)       scal[t]  = expf(-((float)(t * t)) / denom);
        else if (t == 64) scal[64] = alpha;
        return;
    }
    if (blk < 2048) {            // X cast
        const int fi = blk * 256 + t;
        float4 v = ((const float4*)X)[fi];
        ushort4 h = {f2bf(v.x), f2bf(v.y), f2bf(v.z), f2bf(v.w)};
        ((ushort4*)Xh)[fi] = h;
    } else {                     // W cast + w2
        const int fi = (blk - 2048) * 256 + t;
        float4 v = ((const float4*)W)[fi];
        ushort4 h = {f2bf(v.x), f2bf(v.y), f2bf(v.z), f2bf(v.w)};
        ((ushort4*)Wh)[fi] = h;
        float s = v.x * v.x + v.y * v.y + v.z * v.z + v.w * v.w;
        #pragma unroll
        for (int off = 32; off; off >>= 1) s += __shfl_down(s, off);
        if ((t & 63) == 0) w2[fi >> 6] = s;
    }
}

// ---------------- barrier-free bf16 MFMA GEMM + per-row top-2 --------------
// block 128b x 128m, 4 waves (wr: m-half, wc: b-half), wave 64m x 64b.
// Each wave stages EXACTLY the fragments its lanes read into a wave-private
// LDS double-buffer (8KB/chunk): zero s_barrier in the K-loop, per-wave
// vmcnt(8) pipelining only. acc rows = m (thread-local argmin).
__global__ __launch_bounds__(256, 2)
void k_gemm_argmin(const u16* __restrict__ Xh, const u16* __restrict__ Wh,
                   const float* __restrict__ w2, u64* __restrict__ slots) {
    __shared__ char smem[65536];
    const int wg = blockIdx.x;
    const int swz = (wg & 7) * 256 + (wg >> 3);   // XCD-chunked, bijective (2048%8==0)
    const int bt = swz >> 5;                      // 0..63
    const int mt = swz & 31;                      // 0..31
    const int tid = threadIdx.x;
    const int wid = tid >> 6;
    const int lane = tid & 63;
    const int wr = wid >> 1, wc = wid & 1;        // wr: m-half, wc: b-half
    const int b0 = bt * 128, m0 = mt * 128;
    const int rl = lane & 15, g = lane >> 4;

    // per-lane global fragment sources (+ i*16*DIM rows, + c*32 k-cols)
    const u16* wsrc = Wh + (size_t)(m0 + wr * 64 + rl) * DIM + g * 8;
    const u16* xsrc = Xh + (size_t)(b0 + wc * 64 + rl) * DIM + g * 8;
    char* wb = smem + wid * 16384;                // wave-private 16KB (2 x 8KB)

    f32x4 acc[4][4];
    #pragma unroll
    for (int i = 0; i < 4; ++i)
        #pragma unroll
        for (int j = 0; j < 4; ++j) acc[i][j] = (f32x4){0.f, 0.f, 0.f, 0.f};

    #define STAGE(buf, c) do {                                                \
        char* B_ = wb + (buf) * 8192;                                         \
        const int co_ = (c) * 32;                                             \
        gll16(wsrc + (size_t)0 * 16 * DIM + co_, B_ + 0 * 1024);              \
        gll16(wsrc + (size_t)1 * 16 * DIM + co_, B_ + 1 * 1024);              \
        gll16(wsrc + (size_t)2 * 16 * DIM + co_, B_ + 2 * 1024);              \
        gll16(wsrc + (size_t)3 * 16 * DIM + co_, B_ + 3 * 1024);              \
        gll16(xsrc + (size_t)0 * 16 * DIM + co_, B_ + 4 * 1024);              \
        gll16(xsrc + (size_t)1 * 16 * DIM + co_, B_ + 5 * 1024);              \
        gll16(xsrc + (size_t)2 * 16 * DIM + co_, B_ + 6 * 1024);              \
        gll16(xsrc + (size_t)3 * 16 * DIM + co_, B_ + 7 * 1024);              \
    } while (0)

    STAGE(0, 0);
    #pragma unroll
    for (int c = 0; c < 8; ++c) {
        if (c < 7) {
            STAGE((c + 1) & 1, c + 1);
            asm volatile("s_waitcnt vmcnt(8)" ::: "memory");  // own chunk c landed
        } else {
            asm volatile("s_waitcnt vmcnt(0)" ::: "memory");
        }
        __builtin_amdgcn_sched_barrier(0);
        const char* bufc = wb + (c & 1) * 8192 + lane * 16;
        bf16x8 wf[4];
        #pragma unroll
        for (int i = 0; i < 4; ++i)
            wf[i] = *(const bf16x8*)(bufc + i * 1024);
        __builtin_amdgcn_s_setprio(1);
        #pragma unroll
        for (int j = 0; j < 4; ++j) {
            const bf16x8 xf = *(const bf16x8*)(bufc + (4 + j) * 1024);
            #pragma unroll
            for (int i = 0; i < 4; ++i)   // D rows = m, D cols = b
                acc[i][j] = __builtin_amdgcn_mfma_f32_16x16x32_bf16(wf[i], xf, acc[i][j], 0, 0, 0);
        }
        __builtin_amdgcn_s_setprio(0);
    }
    #undef STAGE

    // ---- epilogue: m thread-local -> register top-2, 2 shuffle rounds ----
    float w2v[16];
    #pragma unroll
    for (int ii = 0; ii < 16; ++ii)
        w2v[ii] = w2[m0 + wr * 64 + (ii >> 2) * 16 + g * 4 + (ii & 3)];

    __syncthreads();                    // all waves done with buffers; reuse smem
    u64* ex = (u64*)smem;               // [128 b-local][2 wr][2]

    #pragma unroll
    for (int j = 0; j < 4; ++j) {       // b-col = wc*64 + j*16 + rl
        u64 t1 = ~0ull, t2 = ~0ull;
        #pragma unroll
        for (int i = 0; i < 4; ++i)
            #pragma unroll
            for (int q = 0; q < 4; ++q) {
                const float d = fmaf(-2.0f, acc[i][j][q], w2v[i * 4 + q]);
                ins2(t1, t2, packMin(d, (unsigned)(m0 + wr * 64 + i * 16 + g * 4 + q)));
            }
        #pragma unroll
        for (int off = 16; off <= 32; off <<= 1) {   // merge across g
            const u64 o1 = __shfl_xor(t1, off);
            const u64 o2 = __shfl_xor(t2, off);
            merge2(t1, t2, o1, o2);
        }
        if (lane < 16) {                // g==0 lanes write
            u64* e = ex + ((size_t)(wc * 64 + j * 16 + rl) * 2 + wr) * 2;
            e[0] = t1; e[1] = t2;
        }
    }
    __syncthreads();
    if (tid < 128) {                    // merge wr halves, write global slots
        const u64* e = ex + (size_t)tid * 4;
        u64 a1 = e[0], a2 = e[1];
        merge2(a1, a2, e[2], e[3]);
        slots[(size_t)(b0 + tid) * 64 + mt]      = a1;   // [row][2 ranks][32 mt]
        slots[(size_t)(b0 + tid) * 64 + 32 + mt] = a2;
    }
}

// ---------------- merge slots -> exact top-3 recheck -> locs + bmu ----------
__global__ void k_merge(const u64* __restrict__ slots, const float* __restrict__ X,
                        const float* __restrict__ W, const float* __restrict__ w2,
                        float* __restrict__ out_locs, int* __restrict__ bmu) {
    const int wid = threadIdx.x >> 6, l = threadIdx.x & 63;
    const int row = blockIdx.x * 4 + wid;
    u64 t1 = slots[(size_t)row * 64 + l], t2 = ~0ull, t3 = ~0ull;
    #pragma unroll
    for (int off = 1; off <= 32; off <<= 1) {
        const u64 o1 = __shfl_xor(t1, off);
        const u64 o2 = __shfl_xor(t2, off);
        const u64 o3 = __shfl_xor(t3, off);
        merge3(t1, t2, t3, o1, o2, o3);
    }
    const int cand[3] = {(int)(t1 & 0xFFFFFFFFull), (int)(t2 & 0xFFFFFFFFull),
                         (int)(t3 & 0xFFFFFFFFull)};
    const float4 xv = *(const float4*)(X + (size_t)row * DIM + l * 4);
    float bd = 0.0f; int bm = -1;
    #pragma unroll
    for (int tix = 0; tix < 3; ++tix) {
        const int mc = cand[tix];
        const float4 wv = *(const float4*)(W + (size_t)mc * DIM + l * 4);
        float s = xv.x * wv.x + xv.y * wv.y + xv.z * wv.z + xv.w * wv.w;
        #pragma unroll
        for (int off = 1; off <= 32; off <<= 1) s += __shfl_xor(s, off);
        const float d = w2[mc] - 2.0f * s;
        if (bm < 0 || d < bd || (d == bd && mc < bm)) { bd = d; bm = mc; }
    }
    if (l == 0) {
        out_locs[row * 2 + 0] = (float)(bm >> 6);
        out_locs[row * 2 + 1] = (float)(bm & 63);
        bmu[row] = bm;
    }
}

// ---------------- gather: per-cell sum of assigned rows (no atomics) --------
__global__ void k_gather(const int* __restrict__ bmu, const float* __restrict__ X,
                         float* __restrict__ A, float* __restrict__ cnt) {
    __shared__ int n;
    __shared__ u16 lst[BATCH];
    const int m = blockIdx.x;
    const int t = threadIdx.x;
    if (t == 0) n = 0;
    __syncthreads();
    #pragma unroll
    for (int i = 0; i < BATCH / 256; ++i) {
        const int r = i * 256 + t;
        if (bmu[r] == m) lst[atomicAdd(&n, 1)] = (u16)r;   // LDS atomic, rare hits
    }
    __syncthreads();
    const int nn = n;
    float acc = 0.0f;
    for (int k = 0; k < nn; ++k)
        acc += X[(size_t)lst[k] * DIM + t];
    A[(size_t)m * DIM + t] = acc;
    if (t == 0) cnt[m] = (float)nn;
}

// ---------------- conv pass 1: register-tiled, all-static indices -----------
// grid (65, 4): x<64 -> (gi=x, MJQ=y) main tile; x==64 -> c1 from cnt (y-quarter)
template<int MJQ>
__device__ __forceinline__ void conv1_body(int gi, int t, const float* __restrict__ A,
                                           const float* __restrict__ scal,
                                           float* __restrict__ T1) {
    float a[64];
    #pragma unroll
    for (int gj = 0; gj < 64; ++gj)
        a[gj] = A[(size_t)(gi * 64 + gj) * DIM + t];
    float acc[16];
    #pragma unroll
    for (int i = 0; i < 16; ++i) acc[i] = 0.0f;
    #pragma unroll
    for (int gj = 0; gj < 64; ++gj) {
        #pragma unroll
        for (int mjl = 0; mjl < 16; ++mjl) {
            const int mj = MJQ * 16 + mjl;
            const int dd = (mj >= gj) ? (mj - gj) : (gj - mj);   // static
            acc[mjl] = fmaf(scal[dd], a[gj], acc[mjl]);          // scal[dd]: uniform s-load
        }
    }
    #pragma unroll
    for (int mjl = 0; mjl < 16; ++mjl)
        T1[(size_t)(gi * 64 + MJQ * 16 + mjl) * DIM + t] = acc[mjl];
}

__global__ void k_conv1(const float* __restrict__ A, const float* __restrict__ scal,
                        float* __restrict__ T1, const float* __restrict__ cnt,
                        float* __restrict__ c1) {
    const int t = threadIdx.x;
    if (blockIdx.x == 64) {   // c1[gi][mj] = sum_gj E|mj-gj| cnt[gi][gj]
        #pragma unroll
        for (int k = 0; k < 4; ++k) {
            const int o = blockIdx.y * 1024 + k * 256 + t;
            const int gi = o >> 6, mj = o & 63;
            float acc = 0.0f;
            #pragma unroll
            for (int gj = 0; gj < 64; ++gj) {
                int dd = mj - gj; dd = dd < 0 ? -dd : dd;
                acc += scal[dd] * cnt[gi * 64 + gj];
            }
            c1[o] = acc;
        }
        return;
    }
    const int gi = blockIdx.x;
    switch (blockIdx.y) {
        case 0: conv1_body<0>(gi, t, A, scal, T1); break;
        case 1: conv1_body<1>(gi, t, A, scal, T1); break;
        case 2: conv1_body<2>(gi, t, A, scal, T1); break;
        default: conv1_body<3>(gi, t, A, scal, T1); break;
    }
}

// ---------------- conv pass 2: register-tiled + den + divide ----------------
template<int MIQ>
__device__ __forceinline__ void conv2_body(int mj, int t, const float* __restrict__ T1,
                                           const float* __restrict__ scal,
                                           const float* __restrict__ c1,
                                           float* __restrict__ outw) {
    float t1r[64];
    #pragma unroll
    for (int gi = 0; gi < 64; ++gi)
        t1r[gi] = T1[(size_t)(gi * 64 + mj) * DIM + t];
    __shared__ float dens[16];
    if (t < 16) {                       // den for mi = MIQ*16 + t (hides under t1r loads)
        const int mi = MIQ * 16 + t;
        float dn = 0.0f;
        #pragma unroll
        for (int gi = 0; gi < 64; ++gi) {
            int dd = mi - gi; dd = dd < 0 ? -dd : dd;
            dn = fmaf(scal[dd], c1[gi * 64 + mj], dn);
        }
        dens[t] = dn;
    }
    __syncthreads();
    float acc[16];
    #pragma unroll
    for (int i = 0; i < 16; ++i) acc[i] = 0.0f;
    #pragma unroll
    for (int gi = 0; gi < 64; ++gi) {
        #pragma unroll
        for (int mil = 0; mil < 16; ++mil) {
            const int mi = MIQ * 16 + mil;
            const int dd = (mi >= gi) ? (mi - gi) : (gi - mi);   // static
            acc[mil] = fmaf(scal[dd], t1r[gi], acc[mil]);
        }
    }
    const float al = scal[64];
    #pragma unroll
    for (int mil = 0; mil < 16; ++mil) {
        const int mi = MIQ * 16 + mil;
        outw[(size_t)(mi * 64 + mj) * DIM + t] = (al * acc[mil]) / (al * dens[mil] + 1e-12f);
    }
}

__global__ void k_conv2(const float* __restrict__ T1, const float* __restrict__ scal,
                        const float* __restrict__ c1, float* __restrict__ outw) {
    const int t = threadIdx.x;
    const int mj = blockIdx.x;
    switch (blockIdx.y) {
        case 0: conv2_body<0>(mj, t, T1, scal, c1, outw); break;
        case 1: conv2_body<1>(mj, t, T1, scal, c1, outw); break;
        case 2: conv2_body<2>(mj, t, T1, scal, c1, outw); break;
        default: conv2_body<3>(mj, t, T1, scal, c1, outw); break;
    }
}

// ---------------- launcher ----------------
extern "C" void kernel_launch(void* const* d_in, const int* in_sizes, int n_in,
                              void* d_out, int out_size, void* d_ws, size_t ws_size,
                              hipStream_t stream) {
    const float* X = (const float*)d_in[0];
    const float* W = (const float*)d_in[1];
    const int*   ep = (const int*)d_in[2];
    float* out = (float*)d_out;

    char* ws = (char*)d_ws;
    u64*   slots = (u64*)(ws + 0);                     // 4 MB [8192][64]
    float* T1    = (float*)(ws + 0);                   // alias (slots dead after merge)
    u16*   Xh    = (u16*)(ws + (4u << 20));            // 4 MB
    float* A     = (float*)(ws + (4u << 20));          // alias (Xh dead after gemm)
    float* cnt   = (float*)(ws + (8u << 20));          // 16 KB
    u16*   Wh    = (u16*)(ws + (8u << 20) + 16384);    // 2 MB
    float* w2    = (float*)(ws + (10u << 20) + 16384); // 16 KB
    float* scal  = (float*)(ws + (10u << 20) + 32768); // 65 floats
    float* c1    = (float*)(ws + (10u << 20) + 36864); // 16 KB
    int*   bmu   = (int*)(ws + (10u << 20) + 53248);   // 32 KB

    k_prep<<<3073, 256, 0, stream>>>(X, W, Xh, Wh, w2, ep, scal);
    k_gemm_argmin<<<2048, 256, 0, stream>>>(Xh, Wh, w2, slots);
    k_merge<<<2048, 256, 0, stream>>>(slots, X, W, w2, out, bmu);
    k_gather<<<MCELL, 256, 0, stream>>>(bmu, X, A, cnt);
    k_conv1<<<dim3(65, 4), 256, 0, stream>>>(A, scal, T1, cnt, c1);
    k_conv2<<<dim3(64, 4), 256, 0, stream>>>(T1, scal, c1, out + 16384);
}